// Round 1
// baseline (77.456 us; speedup 1.0000x reference)
//
#include <hip/hip_runtime.h>

// Problem constants (match reference)
#define IN_C   3
#define OUT_C  32
#define KS     5
#define B_N    16
#define H_N    64
#define W_N    64
#define NH     60
#define NW     60

// Each thread computes one output pixel (b, oh, ow) across all 32 channels.
// Key insight: bins are a disjoint uniform partition of [-1,1]; each patch
// element p contributes 16*(f*(1-f))^2 to exactly one channel o=floor((p-l0)/h).
// Accumulators live in a private LDS stripe (dynamic index), stride 33 to
// spread banks.
__global__ __launch_bounds__(64) void local_conv_hist_kernel(
    const float* __restrict__ x,
    const float* __restrict__ lb,
    const float* __restrict__ rb,
    float* __restrict__ out) {

    __shared__ float acc[64 * 33];
    const int lt = threadIdx.x;                 // 0..63
    float* my = &acc[lt * 33];
#pragma unroll
    for (int o = 0; o < OUT_C; ++o) my[o] = 0.0f;

    const int gid = blockIdx.x * 64 + lt;       // 0..57599 (grid sized exactly)
    const int b   = gid / (NH * NW);
    const int rr  = gid % (NH * NW);
    const int oh  = rr / NW;
    const int ow  = rr % NW;

    const float l0    = lb[0];
    const float inv_h = 1.0f / (rb[0] - l0);

    const float* xb = x + (size_t)b * IN_C * (H_N * W_N) + oh * W_N + ow;

#pragma unroll
    for (int c = 0; c < IN_C; ++c) {
        const float* xc = xb + c * (H_N * W_N);
#pragma unroll
        for (int i = 0; i < KS; ++i) {
            const float* xr = xc + i * W_N;
#pragma unroll
            for (int j = 0; j < KS; ++j) {
                const float p = xr[j];
                const float t = (p - l0) * inv_h;
                if (t > 0.0f && t < (float)OUT_C) {
                    const int   o = (int)t;        // floor, since t > 0
                    const float f = t - (float)o;  // fraction within bin
                    const float v = f * (1.0f - f);
                    my[o] += v * v;
                }
            }
        }
    }

    // Write 32 channel outputs for this pixel (coalesced across lanes per o).
    float* ob = out + (size_t)b * OUT_C * (NH * NW) + oh * NW + ow;
#pragma unroll
    for (int o = 0; o < OUT_C; ++o) {
        ob[o * (NH * NW)] = 16.0f * my[o];
    }
}

extern "C" void kernel_launch(void* const* d_in, const int* in_sizes, int n_in,
                              void* d_out, int out_size, void* d_ws, size_t ws_size,
                              hipStream_t stream) {
    const float* x  = (const float*)d_in[0];
    const float* lb = (const float*)d_in[1];
    const float* rb = (const float*)d_in[2];
    float* out = (float*)d_out;

    const int total  = B_N * NH * NW;   // 57600
    const int block  = 64;
    const int grid   = total / block;   // 900, exact

    local_conv_hist_kernel<<<grid, block, 0, stream>>>(x, lb, rb, out);
}

// Round 3
// 66.030 us; speedup vs baseline: 1.1730x; 1.1730x over previous
//
#include <hip/hip_runtime.h>

// Problem constants (match reference)
#define IN_C   3
#define OUT_C  32
#define KS     5
#define B_N    16
#define H_N    64
#define W_N    64
#define NH     60
#define NW     60
#define PIX_PER_IMG (NH * NW)           // 3600
#define TOTAL_PIX   (B_N * PIX_PER_IMG) // 57600
#define ELEMS  (IN_C * KS * KS)         // 75
#define EPW    19                       // elems per wave (waves 0-2: 19, wave 3: 18)

// Bins are a disjoint uniform partition of [-1,1]: each patch element p lands
// in exactly one bin o = floor((p-l0)/h) and contributes 16*(f*(1-f))^2 there.
//
// Decomposition: block = 256 threads = 4 waves over a group of 64 output
// pixels. Lane l <-> pixel; wave w handles patch elements [19w, 19w+19).
// Each thread scatters into a private LDS stripe (stride 33: bank =
// (lane+o)%32, conflict-free). Barrier, then wave w merges+writes channels
// [8w, 8w+8) for all 64 pixels (coalesced 256B stores).
// vs R0: serial LDS RMW chain 75 -> 19 iters, waves 900 -> 3600 (14/CU).
__global__ __launch_bounds__(256) void local_conv_hist_kernel(
    const float* __restrict__ x,
    const float* __restrict__ lb,
    const float* __restrict__ rb,
    float* __restrict__ out) {

    __shared__ float acc[256 * 33];     // 33,792 B -> 4 blocks/CU by LDS
    const int t    = threadIdx.x;
    const int lane = t & 63;
    const int w    = t >> 6;

    float* my = &acc[t * 33];
#pragma unroll
    for (int o = 0; o < OUT_C; ++o) my[o] = 0.0f;
    // no barrier needed: accumulate touches only this thread's own stripe

    const int pix = blockIdx.x * 64 + lane;     // grid sized exactly: 900*64
    const int b   = pix / PIX_PER_IMG;
    const int rr  = pix % PIX_PER_IMG;
    const int oh  = rr / NW;
    const int ow  = rr % NW;

    const float l0    = lb[0];
    const float inv_h = 1.0f / (rb[0] - l0);

    const float* xb = x + (size_t)b * (IN_C * H_N * W_N) + oh * W_N + ow;

    const int e0 = w * EPW;
    const int e1 = (w == 3) ? ELEMS : (e0 + EPW);
#pragma unroll
    for (int k = 0; k < EPW; ++k) {
        const int e = e0 + k;
        if (e < e1) {                           // only trims wave 3's last iter
            const int c   = e / 25;
            const int rem = e % 25;
            const int i   = rem / 5;
            const int j   = rem % 5;
            const float p = xb[c * (H_N * W_N) + i * W_N + j];
            const float tt = (p - l0) * inv_h;
            if (tt > 0.0f && tt < (float)OUT_C) {
                const int   o = (int)tt;        // floor, since tt > 0
                const float f = tt - (float)o;
                const float v = f * (1.0f - f);
                my[o] += v * v;
            }
        }
    }

    __syncthreads();

    // Merge 4 stripes and write: wave w -> channels [8w, 8w+8), lane -> pixel.
    // LDS read bank = (lane + o) % 32: 2 lanes/bank (free). Stores coalesced.
    float* ob = out + (size_t)b * (OUT_C * PIX_PER_IMG) + rr;
#pragma unroll
    for (int k = 0; k < 8; ++k) {
        const int o = w * 8 + k;
        const float s = acc[(0 * 64 + lane) * 33 + o]
                      + acc[(1 * 64 + lane) * 33 + o]
                      + acc[(2 * 64 + lane) * 33 + o]
                      + acc[(3 * 64 + lane) * 33 + o];
        ob[o * PIX_PER_IMG] = 16.0f * s;
    }
}

extern "C" void kernel_launch(void* const* d_in, const int* in_sizes, int n_in,
                              void* d_out, int out_size, void* d_ws, size_t ws_size,
                              hipStream_t stream) {
    const float* x  = (const float*)d_in[0];
    const float* lb = (const float*)d_in[1];
    const float* rb = (const float*)d_in[2];
    float* out = (float*)d_out;

    const int grid = TOTAL_PIX / 64;    // 900 blocks x 256 threads
    local_conv_hist_kernel<<<grid, 256, 0, stream>>>(x, lb, rb, out);
}